// Round 5
// baseline (41012.466 us; speedup 1.0000x reference)
//
#include <hip/hip_runtime.h>
#include <string.h>

#define T_STEPS 256
#define B_SZ    128
#define S_SZ    512
#define D_SZ    256
#define NG      1024   // 4*HID

// ---- static device scratch (graph-capture safe, ws_size-independent) ----
__device__ float g_proj[(size_t)B_SZ * S_SZ * 256];     // 64 MiB, [b][s][d] fp32
__device__ float g_E[(size_t)T_STEPS * B_SZ * 1024];    // 128 MiB, [t][b][j]: emb@W_ih_emb.T
__device__ float g_WihT[512 * 1024];                    // [k][j] fp32 (k<256: emb rows, k>=256: ctx rows)
__device__ float g_WhhT[256 * 1024];                    // [k][j] fp32
__device__ float g_WhT [256 * 256];                     // [k][d] fp32
__device__ float g_WmT [256 * 256];                     // [e][d] fp32
__device__ float g_bias[1024];

__device__ __forceinline__ float tanh_f(float x){
    float r = __expf(2.f * x);          // exp(+inf)=inf, exp(-inf)=0 -> no NaN
    return 1.f - 2.f / (r + 1.f);
}
__device__ __forceinline__ float sigm_f(float x){
    return 1.f / (1.f + __expf(-x));
}

// ---- packing kernels (fp32 -> fp32 transposes) ----

// W_attn: [256][512] -> W_hT [k=256][d=256], W_mT [e=256][d=256]
__global__ void pack_attn(const float* __restrict__ W_attn){
    int id = blockIdx.x * 256 + threadIdx.x;   // 65536
    int d = id >> 8, k = id & 255;
    g_WhT[k * 256 + d] = W_attn[d * 512 + k];
    g_WmT[k * 256 + d] = W_attn[d * 512 + 256 + k];
}

// W_ih [1024][512] -> W_ihT [512][1024]
__global__ void pack_wih(const float* __restrict__ W){
    int id = blockIdx.x * 256 + threadIdx.x;   // 524288
    int j = id >> 9, k = id & 511;
    g_WihT[k * 1024 + j] = W[id];
}
// W_hh [1024][256] -> W_hhT [256][1024]
__global__ void pack_whh(const float* __restrict__ W){
    int id = blockIdx.x * 256 + threadIdx.x;   // 262144
    int j = id >> 8, k = id & 255;
    g_WhhT[k * 1024 + j] = W[id];
}
__global__ void pack_bias(const float* __restrict__ bih, const float* __restrict__ bhh){
    int j = blockIdx.x * 256 + threadIdx.x;    // 1024
    g_bias[j] = bih[j] + bhh[j];
}

// g_proj [b][s][d] = memory[s][b][:] @ W_mT[e][d] + b_attn   (all fp32)
#define PBM 64
#define PBN 64
#define PBK 32
__global__ __launch_bounds__(256) void mem_proj_gemm(
        const float* __restrict__ memory,     // [S][B][256] fp32
        const float* __restrict__ b_attn){
    __shared__ float As[PBK][PBM + 1];
    __shared__ float Bs[PBK][PBN + 1];
    int tid = threadIdx.x;
    int tm = tid >> 4, tn = tid & 15;
    int row0 = blockIdx.x * PBM;             // row r = b*512 + s
    int col0 = blockIdx.y * PBN;
    float acc[4][4] = {};
    for (int k0 = 0; k0 < 256; k0 += PBK){
        int m = tid >> 2, kq = tid & 3;
        int r  = row0 + m;
        int bb = r >> 9, ss = r & 511;
        const float* ap = memory + ((size_t)ss * B_SZ + bb) * 256 + k0 + kq * 8;
        #pragma unroll
        for (int i = 0; i < 8; ++i) As[kq * 8 + i][m] = ap[i];
        int kk = tid >> 3, dq = tid & 7;
        const float* bp = g_WmT + (size_t)(k0 + kk) * 256 + col0 + dq * 8;
        #pragma unroll
        for (int i = 0; i < 8; ++i) Bs[kk][dq * 8 + i] = bp[i];
        __syncthreads();
        #pragma unroll
        for (int k2 = 0; k2 < PBK; ++k2){
            float a[4], bb2[4];
            #pragma unroll
            for (int i = 0; i < 4; ++i) a[i]   = As[k2][tm * 4 + i];
            #pragma unroll
            for (int i = 0; i < 4; ++i) bb2[i] = Bs[k2][tn * 4 + i];
            #pragma unroll
            for (int i = 0; i < 4; ++i)
                #pragma unroll
                for (int j = 0; j < 4; ++j) acc[i][j] += a[i] * bb2[j];
        }
        __syncthreads();
    }
    #pragma unroll
    for (int i = 0; i < 4; ++i){
        int r = row0 + tm * 4 + i;
        float* pp = g_proj + (size_t)r * 256 + col0 + tn * 4;
        #pragma unroll
        for (int j = 0; j < 4; ++j)
            pp[j] = acc[i][j] + b_attn[col0 + tn * 4 + j];
    }
}

// g_E [r=t*B+b][j] = tgt[r][:256] @ g_WihT[k<256][j]   (no bias; added in decode)
__global__ __launch_bounds__(256) void emb_gemm(
        const float* __restrict__ tgt){       // [T][B][256] fp32, rows contiguous
    __shared__ float As[PBK][PBM + 1];
    __shared__ float Bs[PBK][PBN + 1];
    int tid = threadIdx.x;
    int tm = tid >> 4, tn = tid & 15;
    int row0 = blockIdx.x * PBM;             // 512 blocks x 64 rows = 32768
    int col0 = blockIdx.y * PBN;             // 16 blocks x 64 cols = 1024
    float acc[4][4] = {};
    for (int k0 = 0; k0 < 256; k0 += PBK){
        int m = tid >> 2, kq = tid & 3;
        const float* ap = tgt + (size_t)(row0 + m) * 256 + k0 + kq * 8;
        #pragma unroll
        for (int i = 0; i < 8; ++i) As[kq * 8 + i][m] = ap[i];
        int kk = tid >> 3, dq = tid & 7;
        const float* bp = g_WihT + (size_t)(k0 + kk) * 1024 + col0 + dq * 8;
        #pragma unroll
        for (int i = 0; i < 8; ++i) Bs[kk][dq * 8 + i] = bp[i];
        __syncthreads();
        #pragma unroll
        for (int k2 = 0; k2 < PBK; ++k2){
            float a[4], bb2[4];
            #pragma unroll
            for (int i = 0; i < 4; ++i) a[i]   = As[k2][tm * 4 + i];
            #pragma unroll
            for (int i = 0; i < 4; ++i) bb2[i] = Bs[k2][tn * 4 + i];
            #pragma unroll
            for (int i = 0; i < 4; ++i)
                #pragma unroll
                for (int j = 0; j < 4; ++j) acc[i][j] += a[i] * bb2[j];
        }
        __syncthreads();
    }
    #pragma unroll
    for (int i = 0; i < 4; ++i){
        int r = row0 + tm * 4 + i;
        float* pp = g_E + (size_t)r * 1024 + col0 + tn * 4;
        #pragma unroll
        for (int j = 0; j < 4; ++j)
            __builtin_nontemporal_store(acc[i][j], pp + j);
    }
}

// ---- main persistent scan: one block per batch element, 1024 threads ----
// All hot loops batch independent loads (4-8 in flight per wave) to hide
// L2 (~200cy) / MALL (~600cy) latency; accumulation ORDER is unchanged vs
// round 3 so the numeric result is bit-identical.
__global__ __launch_bounds__(1024) void decode_scan(
        const float* __restrict__ memory,    // [S][B][256] fp32
        float* __restrict__ out)             // [T][B][256] fp32
{
    const int b    = blockIdx.x;
    const int tid  = threadIdx.x;
    const int lane = tid & 63;
    const int wave = tid >> 6;          // 16 waves

    __shared__ __align__(16) float h_s[256];
    __shared__ __align__(16) float c_s[256];
    __shared__ __align__(16) float hWh_part[4][256];
    __shared__ __align__(16) float e_s[512];
    __shared__ __align__(16) float attn[512];
    __shared__ __align__(16) float ctx_part[16][256];
    __shared__ __align__(16) float ctx_s[256];
    __shared__ __align__(16) float g_part[4][1024];
    __shared__ __align__(16) float gates[1024];

    if (tid < 256){
        h_s[tid] = 0.f; c_s[tid] = 0.f;
        __builtin_nontemporal_store(0.f, out + (size_t)b * 256 + tid);   // out[0] = zeros
    }
    __syncthreads();

    const float* projb = g_proj + (size_t)b * S_SZ * 256;
    const float* memb  = memory + (size_t)b * 256;

    for (int t = 1; t < T_STEPS; ++t){
        // ---- phase 1: hWh_part[kq][d] = sum over 64 k of h[k]*W_h[d][k] ----
        {
            int d = tid & 255, kq = tid >> 8;   // kq in 0..3, 64 k's each
            float acc = 0.f;
            const float* wp = g_WhT + (size_t)(kq * 64) * 256 + d;
            for (int k0 = 0; k0 < 64; k0 += 8){
                float w[8];
                #pragma unroll
                for (int u = 0; u < 8; ++u)
                    w[u] = wp[(size_t)(k0 + u) * 256];      // 8 loads in flight
                #pragma unroll
                for (int u = 0; u < 8; ++u)
                    acc += h_s[kq * 64 + k0 + u] * w[u];    // same order as before
            }
            hWh_part[kq][d] = acc;
        }
        __syncthreads();

        // ---- phase 2: e[s] = sum_d tanh(proj[s][d] + hWh[d]) ----
        // hWh summed in-register from the 4 partials (saves a pass + barrier)
        {
            float4 p0 = ((const float4*)hWh_part[0])[lane];
            float4 p1 = ((const float4*)hWh_part[1])[lane];
            float4 p2 = ((const float4*)hWh_part[2])[lane];
            float4 p3 = ((const float4*)hWh_part[3])[lane];
            float4 hv;
            hv.x = p0.x + p1.x + p2.x + p3.x;
            hv.y = p0.y + p1.y + p2.y + p3.y;
            hv.z = p0.z + p1.z + p2.z + p3.z;
            hv.w = p0.w + p1.w + p2.w + p3.w;
            const float* pb = projb + (size_t)(wave * 32) * 256;
            for (int i0 = 0; i0 < 32; i0 += 4){
                float4 q[4];
                #pragma unroll
                for (int u = 0; u < 4; ++u)                  // 4 loads in flight
                    q[u] = ((const float4*)(pb + (size_t)(i0 + u) * 256))[lane];
                #pragma unroll
                for (int u = 0; u < 4; ++u){
                    float v = tanh_f(q[u].x + hv.x) + tanh_f(q[u].y + hv.y)
                            + tanh_f(q[u].z + hv.z) + tanh_f(q[u].w + hv.w);
                    #pragma unroll
                    for (int m = 32; m; m >>= 1) v += __shfl_xor(v, m, 64);
                    if (lane == 0) e_s[wave * 32 + i0 + u] = v;
                }
            }
        }
        __syncthreads();

        // ---- phase 3: softmax over s (wave 0 only) ----
        if (wave == 0){
            float v[8]; float mx = -1e30f;
            #pragma unroll
            for (int i = 0; i < 8; ++i){ v[i] = e_s[lane + 64 * i]; mx = fmaxf(mx, v[i]); }
            #pragma unroll
            for (int m = 32; m; m >>= 1) mx = fmaxf(mx, __shfl_xor(mx, m, 64));
            float zs = 0.f;
            #pragma unroll
            for (int i = 0; i < 8; ++i){ v[i] = __expf(v[i] - mx); zs += v[i]; }
            #pragma unroll
            for (int m = 32; m; m >>= 1) zs += __shfl_xor(zs, m, 64);
            float inv = 1.f / zs;
            #pragma unroll
            for (int i = 0; i < 8; ++i) attn[lane + 64 * i] = v[i] * inv;
        }
        __syncthreads();

        // ---- phase 4: ctx[e] = sum_s attn[s]*mem[s][e] ----
        {
            int e4 = tid & 63, sq = tid >> 6;   // 16 s-groups x 32 s
            float a0=0.f, a1=0.f, a2=0.f, a3=0.f;
            // memory[s][b][e]: row stride B*256 = 32768 floats
            const float* mp = memb + (size_t)(sq * 32) * 32768 + 4 * e4;
            for (int s0 = 0; s0 < 32; s0 += 8){
                float4 w[8];
                #pragma unroll
                for (int u = 0; u < 8; ++u)                  // 8 loads in flight
                    w[u] = *(const float4*)(mp + (size_t)(s0 + u) * 32768);
                #pragma unroll
                for (int u = 0; u < 8; ++u){
                    float av = attn[sq * 32 + s0 + u];
                    a0 += av * w[u].x; a1 += av * w[u].y;
                    a2 += av * w[u].z; a3 += av * w[u].w;
                }
            }
            float4 r; r.x=a0; r.y=a1; r.z=a2; r.w=a3;
            ((float4*)ctx_part[sq])[e4] = r;
        }
        __syncthreads();
        if (tid < 256){
            float s = 0.f;
            #pragma unroll
            for (int g = 0; g < 16; ++g) s += ctx_part[g][tid];
            ctx_s[tid] = s;
        }
        __syncthreads();

        // ---- phase 5: gates[j] = ctx@Wc.T + h@W_hh.T + E[t,b,:] + bias ----
        {
            int jq = tid & 255, kh = tid >> 8;  // 4 j's per thread, kh in 0..3
            float a0=0.f, a1=0.f, a2=0.f, a3=0.f;
            const float* src;
            const float* wp;
            if (kh < 2){
                // ctx part: W_ihT rows 256..511
                src = ctx_s + kh * 128;
                wp  = g_WihT + (size_t)(256 + kh * 128) * 1024 + 4 * jq;
            } else {
                // h part: W_hhT rows 0..255
                src = h_s + (kh - 2) * 128;
                wp  = g_WhhT + (size_t)((kh - 2) * 128) * 1024 + 4 * jq;
            }
            for (int k0 = 0; k0 < 128; k0 += 4){
                float4 w[4];
                #pragma unroll
                for (int u = 0; u < 4; ++u)                  // 4 loads in flight
                    w[u] = *(const float4*)(wp + (size_t)(k0 + u) * 1024);
                #pragma unroll
                for (int u = 0; u < 4; ++u){
                    float xv = src[k0 + u];
                    a0 += xv * w[u].x; a1 += xv * w[u].y;
                    a2 += xv * w[u].z; a3 += xv * w[u].w;
                }
            }
            float4 r; r.x=a0; r.y=a1; r.z=a2; r.w=a3;
            ((float4*)g_part[kh])[jq] = r;
        }
        __syncthreads();
        {
            const float* Erow = g_E + ((size_t)t * B_SZ + b) * 1024;
            float ev = __builtin_nontemporal_load(Erow + tid);
            gates[tid] = g_part[0][tid] + g_part[1][tid] + g_part[2][tid]
                       + g_part[3][tid] + ev + g_bias[tid];
        }
        __syncthreads();

        // ---- phase 6: LSTM cell, write h ----
        if (tid < 256){
            float ig = sigm_f(gates[tid]);
            float fg = sigm_f(gates[256 + tid]);
            float gg = tanh_f(gates[512 + tid]);
            float og = sigm_f(gates[768 + tid]);
            float cn = fg * c_s[tid] + ig * gg;
            float hn = og * tanh_f(cn);
            c_s[tid] = cn; h_s[tid] = hn;
            __builtin_nontemporal_store(hn, out + ((size_t)t * B_SZ + b) * 256 + tid);
        }
        __syncthreads();
    }
}

extern "C" void kernel_launch(void* const* d_in, const int* in_sizes, int n_in,
                              void* d_out, int out_size, void* d_ws, size_t ws_size,
                              hipStream_t stream){
    const float* tgt    = (const float*)d_in[0];
    const float* memory = (const float*)d_in[1];
    const float* W_attn = (const float*)d_in[2];
    const float* b_attn = (const float*)d_in[3];
    const float* W_ih   = (const float*)d_in[4];
    const float* W_hh   = (const float*)d_in[5];
    const float* b_ih   = (const float*)d_in[6];
    const float* b_hh   = (const float*)d_in[7];
    float* out = (float*)d_out;
    (void)d_ws; (void)ws_size; (void)in_sizes; (void)n_in; (void)out_size;

    pack_attn<<<256, 256, 0, stream>>>(W_attn);
    pack_wih<<<2048, 256, 0, stream>>>(W_ih);
    pack_whh<<<1024, 256, 0, stream>>>(W_hh);
    pack_bias<<<4, 256, 0, stream>>>(b_ih, b_hh);
    emb_gemm<<<dim3(512, 16), 256, 0, stream>>>(tgt);
    mem_proj_gemm<<<dim3(1024, 4), 256, 0, stream>>>(memory, b_attn);
    decode_scan<<<128, 1024, 0, stream>>>(memory, out);
}

// Round 6
// 15831.174 us; speedup vs baseline: 2.5906x; 2.5906x over previous
//
#include <hip/hip_runtime.h>
#include <string.h>

#define T_STEPS 256
#define B_SZ    128
#define S_SZ    512
#define D_SZ    256
#define NG      1024   // 4*HID

#define SPIN_CAP 50000

// ---- static device scratch (graph-capture safe, ws_size-independent) ----
__device__ float g_proj[(size_t)B_SZ * S_SZ * 256];     // 64 MiB, [b][s][d] fp32
__device__ float g_E[(size_t)T_STEPS * B_SZ * 1024];    // 128 MiB, [t][b][j]: emb@W_ih_emb.T
__device__ float g_WihT[512 * 1024];                    // [k][j] fp32 (k<256 emb rows, k>=256 ctx rows)
__device__ float g_WhhT[256 * 1024];                    // [k][j] fp32
__device__ float g_WhT [256 * 256];                     // [k][d] fp32
__device__ float g_WmT [256 * 256];                     // [e][d] fp32
__device__ float g_bias[1024];

// ---- pair-exchange buffers (block pair per batch element) ----
__device__ float g_ex_e   [B_SZ][512];
__device__ float g_ex_ctx [B_SZ][2][256];
__device__ float g_ex_gate[B_SZ][1024];
__device__ int   g_flags  [2 * B_SZ];

__device__ __forceinline__ float tanh_f(float x){
    float r = __expf(2.f * x);          // exp(+inf)=inf, exp(-inf)=0 -> no NaN
    return 1.f - 2.f / (r + 1.f);
}
__device__ __forceinline__ float sigm_f(float x){
    return 1.f / (1.f + __expf(-x));
}

// ---- packing kernels ----
__global__ void pack_attn(const float* __restrict__ W_attn){
    int id = blockIdx.x * 256 + threadIdx.x;   // 65536
    int d = id >> 8, k = id & 255;
    g_WhT[k * 256 + d] = W_attn[d * 512 + k];
    g_WmT[k * 256 + d] = W_attn[d * 512 + 256 + k];
}
__global__ void pack_wih(const float* __restrict__ W){
    int id = blockIdx.x * 256 + threadIdx.x;   // 524288
    int j = id >> 9, k = id & 511;
    g_WihT[k * 1024 + j] = W[id];
}
__global__ void pack_whh(const float* __restrict__ W){
    int id = blockIdx.x * 256 + threadIdx.x;   // 262144
    int j = id >> 8, k = id & 255;
    g_WhhT[k * 1024 + j] = W[id];
}
__global__ void pack_bias(const float* __restrict__ bih, const float* __restrict__ bhh){
    int j = blockIdx.x * 256 + threadIdx.x;    // 1024
    g_bias[j] = bih[j] + bhh[j];
    if (j < 2 * B_SZ) g_flags[j] = 0;          // reset pair-sync flags every launch
}

// g_proj [b][s][d] = memory[s][b][:] @ W_mT + b_attn
#define PBM 64
#define PBN 64
#define PBK 32
__global__ __launch_bounds__(256) void mem_proj_gemm(
        const float* __restrict__ memory,     // [S][B][256] fp32
        const float* __restrict__ b_attn){
    __shared__ float As[PBK][PBM + 1];
    __shared__ float Bs[PBK][PBN + 1];
    int tid = threadIdx.x;
    int tm = tid >> 4, tn = tid & 15;
    int row0 = blockIdx.x * PBM;             // row r = b*512 + s
    int col0 = blockIdx.y * PBN;
    float acc[4][4] = {};
    for (int k0 = 0; k0 < 256; k0 += PBK){
        int m = tid >> 2, kq = tid & 3;
        int r  = row0 + m;
        int bb = r >> 9, ss = r & 511;
        const float* ap = memory + ((size_t)ss * B_SZ + bb) * 256 + k0 + kq * 8;
        #pragma unroll
        for (int i = 0; i < 8; ++i) As[kq * 8 + i][m] = ap[i];
        int kk = tid >> 3, dq = tid & 7;
        const float* bp = g_WmT + (size_t)(k0 + kk) * 256 + col0 + dq * 8;
        #pragma unroll
        for (int i = 0; i < 8; ++i) Bs[kk][dq * 8 + i] = bp[i];
        __syncthreads();
        #pragma unroll
        for (int k2 = 0; k2 < PBK; ++k2){
            float a[4], bb2[4];
            #pragma unroll
            for (int i = 0; i < 4; ++i) a[i]   = As[k2][tm * 4 + i];
            #pragma unroll
            for (int i = 0; i < 4; ++i) bb2[i] = Bs[k2][tn * 4 + i];
            #pragma unroll
            for (int i = 0; i < 4; ++i)
                #pragma unroll
                for (int j = 0; j < 4; ++j) acc[i][j] += a[i] * bb2[j];
        }
        __syncthreads();
    }
    #pragma unroll
    for (int i = 0; i < 4; ++i){
        int r = row0 + tm * 4 + i;
        float* pp = g_proj + (size_t)r * 256 + col0 + tn * 4;
        #pragma unroll
        for (int j = 0; j < 4; ++j)
            pp[j] = acc[i][j] + b_attn[col0 + tn * 4 + j];
    }
}

// g_E [r=t*B+b][j] = tgt[r][:256] @ g_WihT[k<256][j]
__global__ __launch_bounds__(256) void emb_gemm(
        const float* __restrict__ tgt){       // [T][B][256] fp32
    __shared__ float As[PBK][PBM + 1];
    __shared__ float Bs[PBK][PBN + 1];
    int tid = threadIdx.x;
    int tm = tid >> 4, tn = tid & 15;
    int row0 = blockIdx.x * PBM;
    int col0 = blockIdx.y * PBN;
    float acc[4][4] = {};
    for (int k0 = 0; k0 < 256; k0 += PBK){
        int m = tid >> 2, kq = tid & 3;
        const float* ap = tgt + (size_t)(row0 + m) * 256 + k0 + kq * 8;
        #pragma unroll
        for (int i = 0; i < 8; ++i) As[kq * 8 + i][m] = ap[i];
        int kk = tid >> 3, dq = tid & 7;
        const float* bp = g_WihT + (size_t)(k0 + kk) * 1024 + col0 + dq * 8;
        #pragma unroll
        for (int i = 0; i < 8; ++i) Bs[kk][dq * 8 + i] = bp[i];
        __syncthreads();
        #pragma unroll
        for (int k2 = 0; k2 < PBK; ++k2){
            float a[4], bb2[4];
            #pragma unroll
            for (int i = 0; i < 4; ++i) a[i]   = As[k2][tm * 4 + i];
            #pragma unroll
            for (int i = 0; i < 4; ++i) bb2[i] = Bs[k2][tn * 4 + i];
            #pragma unroll
            for (int i = 0; i < 4; ++i)
                #pragma unroll
                for (int j = 0; j < 4; ++j) acc[i][j] += a[i] * bb2[j];
        }
        __syncthreads();
    }
    #pragma unroll
    for (int i = 0; i < 4; ++i){
        int r = row0 + tm * 4 + i;
        float* pp = g_E + (size_t)r * 1024 + col0 + tn * 4;
        #pragma unroll
        for (int j = 0; j < 4; ++j)
            __builtin_nontemporal_store(acc[i][j], pp + j);
    }
}

// Pair sync: publisher's data stores are agent-scope atomics (device-coherent
// point); the RELEASE flag store orders them before the flag. Reader spins
// relaxed (no acquire -> no L2 invalidate, weights stay cached), then reads
// partner data with agent-scope atomic loads. Co-residency is guaranteed by
// grid=256=#CUs (all blocks resident at t=0), so the spin terminates; the
// bounded cap + poison converts any surprise into a fast wrong answer.
__device__ __forceinline__ void pair_sync(int myid, int partner, int target, int* dead){
    __syncthreads();                     // all lanes done publishing
    if (threadIdx.x == 0 && !*dead){
        __hip_atomic_store(&g_flags[myid], target, __ATOMIC_RELEASE, __HIP_MEMORY_SCOPE_AGENT);
        int spins = 0;
        while (__hip_atomic_load(&g_flags[partner], __ATOMIC_RELAXED, __HIP_MEMORY_SCOPE_AGENT) < target){
            __builtin_amdgcn_s_sleep(2);
            if (++spins > SPIN_CAP){ *dead = 1; break; }
        }
    }
    __syncthreads();                     // flag observed -> partner data readable
}

// ---- main persistent scan: TWO blocks per batch element, 512 threads ----
// block p of pair (b = bid>>1, p = bid&1): owns s-half [p*256, p*256+256)
// for energy/ctx and gate j-half [p*512, p*512+512).
__global__ __launch_bounds__(512) void decode_scan(
        const float* __restrict__ memory,    // [S][B][256] fp32
        float* __restrict__ out)             // [T][B][256] fp32
{
    const int bid  = blockIdx.x;        // 0..255
    const int b    = bid >> 1;
    const int p    = bid & 1;
    const int partner = bid ^ 1;
    const int tid  = threadIdx.x;
    const int lane = tid & 63;
    const int wave = tid >> 6;          // 8 waves
    const int s0   = p * 256;
    const int j0   = p * 512;

    __shared__ __align__(16) float h_s[256];
    __shared__ __align__(16) float c_s[256];
    __shared__ __align__(16) float hWh_part[2][256];
    __shared__ __align__(16) float e_s[512];
    __shared__ __align__(16) float attn[512];
    __shared__ __align__(16) float ctx_part[8][256];
    __shared__ __align__(16) float ctx_s[256];
    __shared__ __align__(16) float g_part[4][512];
    __shared__ __align__(16) float gates[1024];
    __shared__ int s_dead;

    if (tid < 256){
        h_s[tid] = 0.f; c_s[tid] = 0.f;
        if (p == 0)
            __builtin_nontemporal_store(0.f, out + (size_t)b * 256 + tid); // out[0]=0
    }
    if (tid == 0) s_dead = 0;
    __syncthreads();

    const float* projb = g_proj + ((size_t)b * S_SZ + s0) * 256;
    const float* memb  = memory + (size_t)b * 256;

    int ctr = 0;
    for (int t = 1; t < T_STEPS; ++t){
        // ---- phase 1: hWh_part[kq][d] = sum_{128 k} h[k]*W_h[d][k] (redundant) ----
        {
            int d = tid & 255, kq = tid >> 8;   // kq 0..1
            float acc = 0.f;
            const float* wp = g_WhT + (size_t)(kq * 128) * 256 + d;
            #pragma unroll 8
            for (int k = 0; k < 128; ++k)
                acc += h_s[kq * 128 + k] * wp[(size_t)k * 256];
            hWh_part[kq][d] = acc;
        }
        __syncthreads();

        // ---- phase 2: e[s] = sum_d tanh(proj[s][d] + hWh[d]) over own s-half ----
        {
            float4 p0 = ((const float4*)hWh_part[0])[lane];
            float4 p1 = ((const float4*)hWh_part[1])[lane];
            float4 hv;
            hv.x = p0.x + p1.x; hv.y = p0.y + p1.y;
            hv.z = p0.z + p1.z; hv.w = p0.w + p1.w;
            #pragma unroll 4
            for (int i = 0; i < 32; ++i){
                int sl = wave * 32 + i;           // 8 waves x 32 = 256 local s
                float4 q = ((const float4*)(projb + (size_t)sl * 256))[lane];
                float v = tanh_f(q.x + hv.x) + tanh_f(q.y + hv.y)
                        + tanh_f(q.z + hv.z) + tanh_f(q.w + hv.w);
                #pragma unroll
                for (int m = 32; m; m >>= 1) v += __shfl_xor(v, m, 64);
                if (lane == 0) e_s[s0 + sl] = v;
            }
        }
        __syncthreads();
        // publish own e-half, exchange with partner
        if (tid < 256)
            __hip_atomic_store(&g_ex_e[b][s0 + tid], e_s[s0 + tid],
                               __ATOMIC_RELAXED, __HIP_MEMORY_SCOPE_AGENT);
        pair_sync(bid, partner, ++ctr, &s_dead);
        if (tid < 256){
            int so = s0 ^ 256;
            e_s[so + tid] = __hip_atomic_load(&g_ex_e[b][so + tid],
                               __ATOMIC_RELAXED, __HIP_MEMORY_SCOPE_AGENT);
        }
        __syncthreads();

        // ---- phase 3: softmax over all 512 s (redundant, wave 0) ----
        if (wave == 0){
            float v[8]; float mx = -1e30f;
            #pragma unroll
            for (int i = 0; i < 8; ++i){ v[i] = e_s[lane + 64 * i]; mx = fmaxf(mx, v[i]); }
            #pragma unroll
            for (int m = 32; m; m >>= 1) mx = fmaxf(mx, __shfl_xor(mx, m, 64));
            float zs = 0.f;
            #pragma unroll
            for (int i = 0; i < 8; ++i){ v[i] = __expf(v[i] - mx); zs += v[i]; }
            #pragma unroll
            for (int m = 32; m; m >>= 1) zs += __shfl_xor(zs, m, 64);
            float inv = 1.f / zs;
            #pragma unroll
            for (int i = 0; i < 8; ++i) attn[lane + 64 * i] = v[i] * inv;
        }
        __syncthreads();

        // ---- phase 4: partial ctx over own s-half ----
        {
            int e4 = tid & 63, sq = tid >> 6;   // 8 groups x 32 s (own half)
            float a0=0.f, a1=0.f, a2=0.f, a3=0.f;
            const float* mp = memb + (size_t)(s0 + sq * 32) * 32768 + 4 * e4;
            #pragma unroll 4
            for (int s = 0; s < 32; ++s){
                float av = attn[s0 + sq * 32 + s];
                float4 w = *(const float4*)(mp + (size_t)s * 32768);
                a0 += av * w.x; a1 += av * w.y;
                a2 += av * w.z; a3 += av * w.w;
            }
            float4 r; r.x=a0; r.y=a1; r.z=a2; r.w=a3;
            ((float4*)ctx_part[sq])[e4] = r;
        }
        __syncthreads();
        if (tid < 256){
            float s = 0.f;
            #pragma unroll
            for (int g = 0; g < 8; ++g) s += ctx_part[g][tid];
            ctx_part[0][tid] = s;               // keep own partial
            __hip_atomic_store(&g_ex_ctx[b][p][tid], s,
                               __ATOMIC_RELAXED, __HIP_MEMORY_SCOPE_AGENT);
        }
        pair_sync(bid, partner, ++ctr, &s_dead);
        if (tid < 256){
            float o = __hip_atomic_load(&g_ex_ctx[b][p ^ 1][tid],
                               __ATOMIC_RELAXED, __HIP_MEMORY_SCOPE_AGENT);
            ctx_s[tid] = ctx_part[0][tid] + o;
        }
        __syncthreads();

        // ---- phase 5: own gate j-half = ctx@Wc.T + h@W_hh.T + E + bias ----
        {
            int jq = tid & 127, kh = tid >> 7;  // 4 j's per thread, kh 0..3
            float a0=0.f, a1=0.f, a2=0.f, a3=0.f;
            const float* src;
            const float* wp;
            if (kh < 2){
                src = ctx_s + kh * 128;
                wp  = g_WihT + (size_t)(256 + kh * 128) * 1024 + j0 + 4 * jq;
            } else {
                src = h_s + (kh - 2) * 128;
                wp  = g_WhhT + (size_t)((kh - 2) * 128) * 1024 + j0 + 4 * jq;
            }
            #pragma unroll 4
            for (int k = 0; k < 128; ++k){
                float xv = src[k];
                float4 w = *(const float4*)(wp + (size_t)k * 1024);
                a0 += xv * w.x; a1 += xv * w.y;
                a2 += xv * w.z; a3 += xv * w.w;
            }
            float4 r; r.x=a0; r.y=a1; r.z=a2; r.w=a3;
            ((float4*)g_part[kh])[jq] = r;
        }
        __syncthreads();
        {
            const float* Erow = g_E + ((size_t)t * B_SZ + b) * 1024 + j0;
            float ev = __builtin_nontemporal_load(Erow + tid);
            float gv = g_part[0][tid] + g_part[1][tid] + g_part[2][tid]
                     + g_part[3][tid] + ev + g_bias[j0 + tid];
            gates[j0 + tid] = gv;
            __hip_atomic_store(&g_ex_gate[b][j0 + tid], gv,
                               __ATOMIC_RELAXED, __HIP_MEMORY_SCOPE_AGENT);
        }
        pair_sync(bid, partner, ++ctr, &s_dead);
        {
            int jo = j0 ^ 512;
            gates[jo + tid] = __hip_atomic_load(&g_ex_gate[b][jo + tid],
                               __ATOMIC_RELAXED, __HIP_MEMORY_SCOPE_AGENT);
        }
        __syncthreads();

        // ---- phase 6: LSTM cell (redundant), p==0 writes out ----
        if (tid < 256){
            float ig = sigm_f(gates[tid]);
            float fg = sigm_f(gates[256 + tid]);
            float gg = tanh_f(gates[512 + tid]);
            float og = sigm_f(gates[768 + tid]);
            float cn = fg * c_s[tid] + ig * gg;
            float hn = og * tanh_f(cn);
            c_s[tid] = cn; h_s[tid] = hn;
            if (p == 0)
                __builtin_nontemporal_store(hn, out + ((size_t)t * B_SZ + b) * 256 + tid);
        }
        __syncthreads();
    }
}

extern "C" void kernel_launch(void* const* d_in, const int* in_sizes, int n_in,
                              void* d_out, int out_size, void* d_ws, size_t ws_size,
                              hipStream_t stream){
    const float* tgt    = (const float*)d_in[0];
    const float* memory = (const float*)d_in[1];
    const float* W_attn = (const float*)d_in[2];
    const float* b_attn = (const float*)d_in[3];
    const float* W_ih   = (const float*)d_in[4];
    const float* W_hh   = (const float*)d_in[5];
    const float* b_ih   = (const float*)d_in[6];
    const float* b_hh   = (const float*)d_in[7];
    float* out = (float*)d_out;
    (void)d_ws; (void)ws_size; (void)in_sizes; (void)n_in; (void)out_size;

    pack_attn<<<256, 256, 0, stream>>>(W_attn);
    pack_wih<<<2048, 256, 0, stream>>>(W_ih);
    pack_whh<<<1024, 256, 0, stream>>>(W_hh);
    pack_bias<<<4, 256, 0, stream>>>(b_ih, b_hh);
    emb_gemm<<<dim3(512, 16), 256, 0, stream>>>(tgt);
    mem_proj_gemm<<<dim3(1024, 4), 256, 0, stream>>>(memory, b_attn);
    decode_scan<<<256, 512, 0, stream>>>(memory, out);
}

// Round 7
// 12974.580 us; speedup vs baseline: 3.1610x; 1.2202x over previous
//
#include <hip/hip_runtime.h>
#include <string.h>

#define T_STEPS 256
#define B_SZ    128
#define S_SZ    512
#define D_SZ    256
#define NG      1024   // 4*HID

// ---- static device scratch (graph-capture safe, ws_size-independent) ----
__device__ float g_projT[(size_t)B_SZ * 256 * 512];     // 64 MiB, [b][d][s] fp32 (TRANSPOSED)
__device__ float g_E[(size_t)T_STEPS * B_SZ * 1024];    // 128 MiB, [t][b][j]: emb@W_ih_emb.T
__device__ float g_WihT[512 * 1024];                    // [k][j] fp32 (k<256 emb rows, k>=256 ctx rows)
__device__ float g_WhhT[256 * 1024];                    // [k][j] fp32
__device__ float g_WhT [256 * 256];                     // [k][d] fp32
__device__ float g_bias[1024];

__device__ __forceinline__ float tanh_f(float x){
    float r = __expf(2.f * x);          // exp(+inf)=inf, exp(-inf)=0 -> no NaN
    return 1.f - 2.f / (r + 1.f);
}
__device__ __forceinline__ float sigm_f(float x){
    return 1.f / (1.f + __expf(-x));
}

// ---- packing kernels ----
// W_attn: [256][512] -> W_hT [k=256][d=256] (W_m read directly by the GEMM)
__global__ void pack_attn(const float* __restrict__ W_attn){
    int id = blockIdx.x * 256 + threadIdx.x;   // 65536
    int d = id >> 8, k = id & 255;
    g_WhT[k * 256 + d] = W_attn[d * 512 + k];
}
__global__ void pack_wih(const float* __restrict__ W){
    int id = blockIdx.x * 256 + threadIdx.x;   // 524288
    int j = id >> 9, k = id & 511;
    g_WihT[k * 1024 + j] = W[id];
}
__global__ void pack_whh(const float* __restrict__ W){
    int id = blockIdx.x * 256 + threadIdx.x;   // 262144
    int j = id >> 8, k = id & 255;
    g_WhhT[k * 1024 + j] = W[id];
}
__global__ void pack_bias(const float* __restrict__ bih, const float* __restrict__ bhh){
    int j = blockIdx.x * 256 + threadIdx.x;    // 1024
    g_bias[j] = bih[j] + bhh[j];
}

// g_projT[b][d][s] = sum_e memory[s][b][e] * W_attn[d][256+e] + b_attn[d]
// GEMM: M = d (256), N = r = b*512+s (65536), K = e (256).
__global__ __launch_bounds__(256) void mem_projT_gemm(
        const float* __restrict__ memory,     // [S][B][256] fp32
        const float* __restrict__ W_attn,     // [256][512] fp32
        const float* __restrict__ b_attn){
    __shared__ float As[32][65];   // [e'][d']
    __shared__ float Bs[32][65];   // [e'][r']
    int tid = threadIdx.x;
    int tm = tid >> 4, tn = tid & 15;
    int row0 = blockIdx.x * 64;              // d tile (4 tiles)
    int col0 = blockIdx.y * 64;              // r tile (1024 tiles); 64 | 512 so one b per tile
    float acc[4][4] = {};
    for (int k0 = 0; k0 < 256; k0 += 32){
        int m = tid >> 2, kq = tid & 3;
        // A: W_m rows d = row0+m, e = k0+kq*8 .. +8
        const float* ap = W_attn + (size_t)(row0 + m) * 512 + 256 + k0 + kq * 8;
        #pragma unroll
        for (int i = 0; i < 8; ++i) As[kq * 8 + i][m] = ap[i];
        // B: mem[e][r]: r = col0+m -> (b,s); e = k0+kq*8 .. +8
        int r  = col0 + m;
        int bb = r >> 9, ss = r & 511;
        const float* bp = memory + ((size_t)ss * B_SZ + bb) * 256 + k0 + kq * 8;
        #pragma unroll
        for (int i = 0; i < 8; ++i) Bs[kq * 8 + i][m] = bp[i];
        __syncthreads();
        #pragma unroll
        for (int k2 = 0; k2 < 32; ++k2){
            float a[4], bv[4];
            #pragma unroll
            for (int i = 0; i < 4; ++i) a[i]  = As[k2][tm * 4 + i];
            #pragma unroll
            for (int i = 0; i < 4; ++i) bv[i] = Bs[k2][tn * 4 + i];
            #pragma unroll
            for (int i = 0; i < 4; ++i)
                #pragma unroll
                for (int j = 0; j < 4; ++j) acc[i][j] += a[i] * bv[j];
        }
        __syncthreads();
    }
    int bb_o = col0 >> 9;
    int s_o  = (col0 & 511) + tn * 4;
    #pragma unroll
    for (int i = 0; i < 4; ++i){
        int d = row0 + tm * 4 + i;
        float bi = b_attn[d];
        float* pp = g_projT + ((size_t)bb_o * 256 + d) * 512 + s_o;
        #pragma unroll
        for (int j = 0; j < 4; ++j)
            pp[j] = acc[i][j] + bi;       // coalesced along s
    }
}

// g_E [r=t*B+b][j] = tgt[r][:256] @ g_WihT[k<256][j]
__global__ __launch_bounds__(256) void emb_gemm(
        const float* __restrict__ tgt){       // [T][B][256] fp32
    __shared__ float As[32][65];
    __shared__ float Bs[32][65];
    int tid = threadIdx.x;
    int tm = tid >> 4, tn = tid & 15;
    int row0 = blockIdx.x * 64;
    int col0 = blockIdx.y * 64;
    float acc[4][4] = {};
    for (int k0 = 0; k0 < 256; k0 += 32){
        int m = tid >> 2, kq = tid & 3;
        const float* ap = tgt + (size_t)(row0 + m) * 256 + k0 + kq * 8;
        #pragma unroll
        for (int i = 0; i < 8; ++i) As[kq * 8 + i][m] = ap[i];
        int kk = tid >> 3, dq = tid & 7;
        const float* bp = g_WihT + (size_t)(k0 + kk) * 1024 + col0 + dq * 8;
        #pragma unroll
        for (int i = 0; i < 8; ++i) Bs[kk][dq * 8 + i] = bp[i];
        __syncthreads();
        #pragma unroll
        for (int k2 = 0; k2 < 32; ++k2){
            float a[4], bv[4];
            #pragma unroll
            for (int i = 0; i < 4; ++i) a[i]  = As[k2][tm * 4 + i];
            #pragma unroll
            for (int i = 0; i < 4; ++i) bv[i] = Bs[k2][tn * 4 + i];
            #pragma unroll
            for (int i = 0; i < 4; ++i)
                #pragma unroll
                for (int j = 0; j < 4; ++j) acc[i][j] += a[i] * bv[j];
        }
        __syncthreads();
    }
    #pragma unroll
    for (int i = 0; i < 4; ++i){
        int r = row0 + tm * 4 + i;
        float* pp = g_E + (size_t)r * 1024 + col0 + tn * 4;
        #pragma unroll
        for (int j = 0; j < 4; ++j)
            __builtin_nontemporal_store(acc[i][j], pp + j);
    }
}

// ---- main persistent scan: one block per batch element, 1024 threads ----
__global__ __launch_bounds__(1024) void decode_scan(
        const float* __restrict__ memory,    // [S][B][256] fp32
        float* __restrict__ out)             // [T][B][256] fp32
{
    const int b    = blockIdx.x;
    const int tid  = threadIdx.x;
    const int lane = tid & 63;
    const int wave = tid >> 6;          // 16 waves

    __shared__ __align__(16) float h_s[256];
    __shared__ __align__(16) float c_s[256];
    __shared__ __align__(16) float hWh_part[4][256];
    __shared__ __align__(16) float hWh[256];
    __shared__ __align__(16) float e_part[16][512];   // per-d-group partials
    __shared__ __align__(16) float e_s[512];
    __shared__ __align__(16) float attn[512];
    __shared__ __align__(16) float ctx_part[16][256];
    __shared__ __align__(16) float ctx_s[256];
    __shared__ __align__(16) float g_part[4][1024];
    __shared__ __align__(16) float gates[1024];

    if (tid < 256){
        h_s[tid] = 0.f; c_s[tid] = 0.f;
        __builtin_nontemporal_store(0.f, out + (size_t)b * 256 + tid);   // out[0] = zeros
    }
    __syncthreads();

    const float* projTb = g_projT + (size_t)b * 256 * 512;   // [d][s]
    const float* memb   = memory + (size_t)b * 256;

    for (int t = 1; t < T_STEPS; ++t){
        // E-row prefetch: issued now, consumed after phase 5 (hides LLC latency)
        float ev = __builtin_nontemporal_load(
                        g_E + ((size_t)t * B_SZ + b) * 1024 + tid);

        // ---- phase 1: hWh[d] = sum_k h[k] * W_h[d][k] ----
        {
            int d = tid & 255, kq = tid >> 8;   // kq in 0..3, 64 k's each
            float acc = 0.f;
            const float* wp = g_WhT + (size_t)(kq * 64) * 256 + d;
            #pragma unroll 8
            for (int k = 0; k < 64; ++k)
                acc += h_s[kq * 64 + k] * wp[(size_t)k * 256];
            hWh_part[kq][d] = acc;
        }
        __syncthreads();
        if (tid < 256)
            hWh[tid] = hWh_part[0][tid] + hWh_part[1][tid] + hWh_part[2][tid] + hWh_part[3][tid];
        __syncthreads();

        // ---- phase 2 (rewritten): wave w owns d in [16w,16w+16), lane owns 8 s.
        // Coalesced 2KB wave reads from projT[d][s]; zero shuffles.
        {
            const float* pT = projTb + (size_t)(wave * 16) * 512 + lane * 8;
            float4 aA = {0.f,0.f,0.f,0.f}, aB = {0.f,0.f,0.f,0.f};
            #pragma unroll 2
            for (int dd = 0; dd < 16; ++dd){
                float hw = hWh[wave * 16 + dd];
                const float4* rp = (const float4*)(pT + (size_t)dd * 512);
                float4 q1 = rp[0];
                float4 q2 = rp[1];
                aA.x += tanh_f(q1.x + hw); aA.y += tanh_f(q1.y + hw);
                aA.z += tanh_f(q1.z + hw); aA.w += tanh_f(q1.w + hw);
                aB.x += tanh_f(q2.x + hw); aB.y += tanh_f(q2.y + hw);
                aB.z += tanh_f(q2.z + hw); aB.w += tanh_f(q2.w + hw);
            }
            float4* ep = (float4*)&e_part[wave][lane * 8];
            ep[0] = aA; ep[1] = aB;
        }
        __syncthreads();
        if (tid < 512){
            float v = 0.f;
            #pragma unroll
            for (int w2 = 0; w2 < 16; ++w2) v += e_part[w2][tid];
            e_s[tid] = v;
        }
        __syncthreads();

        // ---- phase 3: softmax over s (wave 0 only) ----
        if (wave == 0){
            float v[8]; float mx = -1e30f;
            #pragma unroll
            for (int i = 0; i < 8; ++i){ v[i] = e_s[lane + 64 * i]; mx = fmaxf(mx, v[i]); }
            #pragma unroll
            for (int m = 32; m; m >>= 1) mx = fmaxf(mx, __shfl_xor(mx, m, 64));
            float zs = 0.f;
            #pragma unroll
            for (int i = 0; i < 8; ++i){ v[i] = __expf(v[i] - mx); zs += v[i]; }
            #pragma unroll
            for (int m = 32; m; m >>= 1) zs += __shfl_xor(zs, m, 64);
            float inv = 1.f / zs;
            #pragma unroll
            for (int i = 0; i < 8; ++i) attn[lane + 64 * i] = v[i] * inv;
        }
        __syncthreads();

        // ---- phase 4: ctx[e] = sum_s attn[s]*mem[s][e] ----
        {
            int e4 = tid & 63, sq = tid >> 6;   // 16 s-groups x 32 s
            float a0=0.f, a1=0.f, a2=0.f, a3=0.f;
            const float* mp = memb + (size_t)(sq * 32) * 32768 + 4 * e4;
            #pragma unroll 4
            for (int s = 0; s < 32; ++s){
                float av = attn[sq * 32 + s];
                float4 w = *(const float4*)(mp + (size_t)s * 32768);
                a0 += av * w.x; a1 += av * w.y;
                a2 += av * w.z; a3 += av * w.w;
            }
            float4 r; r.x=a0; r.y=a1; r.z=a2; r.w=a3;
            ((float4*)ctx_part[sq])[e4] = r;
        }
        __syncthreads();
        if (tid < 256){
            float s = 0.f;
            #pragma unroll
            for (int g = 0; g < 16; ++g) s += ctx_part[g][tid];
            ctx_s[tid] = s;
        }
        __syncthreads();

        // ---- phase 5: gates[j] = ctx@Wc.T + h@W_hh.T + E[t,b,:] + bias ----
        {
            int jq = tid & 255, kh = tid >> 8;  // 4 j's per thread, kh in 0..3
            float a0=0.f, a1=0.f, a2=0.f, a3=0.f;
            const float* src;
            const float* wp;
            if (kh < 2){
                src = ctx_s + kh * 128;
                wp  = g_WihT + (size_t)(256 + kh * 128) * 1024 + 4 * jq;
            } else {
                src = h_s + (kh - 2) * 128;
                wp  = g_WhhT + (size_t)((kh - 2) * 128) * 1024 + 4 * jq;
            }
            #pragma unroll 4
            for (int k = 0; k < 128; ++k){
                float xv = src[k];
                float4 w = *(const float4*)(wp + (size_t)k * 1024);
                a0 += xv * w.x; a1 += xv * w.y;
                a2 += xv * w.z; a3 += xv * w.w;
            }
            float4 r; r.x=a0; r.y=a1; r.z=a2; r.w=a3;
            ((float4*)g_part[kh])[jq] = r;
        }
        __syncthreads();
        gates[tid] = g_part[0][tid] + g_part[1][tid] + g_part[2][tid]
                   + g_part[3][tid] + ev + g_bias[tid];
        __syncthreads();

        // ---- phase 6: LSTM cell, write h ----
        if (tid < 256){
            float ig = sigm_f(gates[tid]);
            float fg = sigm_f(gates[256 + tid]);
            float gg = tanh_f(gates[512 + tid]);
            float og = sigm_f(gates[768 + tid]);
            float cn = fg * c_s[tid] + ig * gg;
            float hn = og * tanh_f(cn);
            c_s[tid] = cn; h_s[tid] = hn;
            __builtin_nontemporal_store(hn, out + ((size_t)t * B_SZ + b) * 256 + tid);
        }
        __syncthreads();
    }
}

extern "C" void kernel_launch(void* const* d_in, const int* in_sizes, int n_in,
                              void* d_out, int out_size, void* d_ws, size_t ws_size,
                              hipStream_t stream){
    const float* tgt    = (const float*)d_in[0];
    const float* memory = (const float*)d_in[1];
    const float* W_attn = (const float*)d_in[2];
    const float* b_attn = (const float*)d_in[3];
    const float* W_ih   = (const float*)d_in[4];
    const float* W_hh   = (const float*)d_in[5];
    const float* b_ih   = (const float*)d_in[6];
    const float* b_hh   = (const float*)d_in[7];
    float* out = (float*)d_out;
    (void)d_ws; (void)ws_size; (void)in_sizes; (void)n_in; (void)out_size;

    pack_attn<<<256, 256, 0, stream>>>(W_attn);
    pack_wih<<<2048, 256, 0, stream>>>(W_ih);
    pack_whh<<<1024, 256, 0, stream>>>(W_hh);
    pack_bias<<<4, 256, 0, stream>>>(b_ih, b_hh);
    emb_gemm<<<dim3(512, 16), 256, 0, stream>>>(tgt);
    mem_projT_gemm<<<dim3(4, 1024), 256, 0, stream>>>(memory, W_attn, b_attn);
    decode_scan<<<128, 1024, 0, stream>>>(memory, out);
}